// Round 9
// baseline (858.802 us; speedup 1.0000x reference)
//
#include <hip/hip_runtime.h>

using u16 = unsigned short;
using u32 = unsigned int;
typedef __attribute__((ext_vector_type(8))) short s16x8;
typedef __attribute__((ext_vector_type(4))) float f32x4;

typedef uint4   __attribute__((may_alias)) uint4a;
typedef ushort4 __attribute__((may_alias)) ushort4a;
typedef float4  __attribute__((may_alias)) float4a;
typedef u16     __attribute__((may_alias)) u16a;
typedef s16x8   __attribute__((may_alias)) s16x8a;

#define D_ 1024
#define H_ 4
#define B_ 4
#define S_ 2048
#define M_ 8192  /* B_*S_ */

#define BM 128
#define BN 128
#define BK 32

__device__ __forceinline__ float bf2f(u16 u) { return __uint_as_float(((u32)u) << 16); }
__device__ __forceinline__ u16 f2bf(float f) {
  u32 b = __float_as_uint(f);
  return (u16)((b + 0x7fffu + ((b >> 16) & 1u)) >> 16);
}

__device__ __forceinline__ void gload_lds16(const u16* g, u16* l) {
  __builtin_amdgcn_global_load_lds(
      (const __attribute__((address_space(1))) void*)g,
      (__attribute__((address_space(3))) void*)l, 16, 0, 0);
}

// XCD-bijective swizzle + 4x4 quad decomposition, z folded into x-axis.
// Requires nwg%16==0, (gx*gz)%4==0, gy%4==0 (all our grids satisfy).
__device__ __forceinline__ void swz_decomp(int& x, int& y, int& z) {
  const int gx = gridDim.x, gy = gridDim.y;
  const int nwg = gx * gy * gridDim.z;
  const int flat = (blockIdx.z * gy + blockIdx.y) * gx + blockIdx.x;
  const int swz = (flat & 7) * (nwg >> 3) + (flat >> 3);
  const int t = swz >> 4, i = swz & 15;
  const int tiles_X = (gx * gridDim.z) >> 2;
  const int X = (t % tiles_X) * 4 + (i & 3);
  y = (t / tiles_X) * 4 + (i >> 2);
  z = X / gx;
  x = X % gx;
}

// ---------------- f32 -> bf16 convert ----------------
__global__ __launch_bounds__(256) void cvt_f32_bf16(const float* __restrict__ in,
                                                    u16* __restrict__ out, long n4) {
  long stride = (long)gridDim.x * blockDim.x;
  for (long i = (long)blockIdx.x * blockDim.x + threadIdx.x; i < n4; i += stride) {
    float4 v = ((const float4a*)in)[i];
    ushort4 o;
    o.x = f2bf(v.x); o.y = f2bf(v.y); o.z = f2bf(v.z); o.w = f2bf(v.w);
    ((ushort4a*)out)[i] = o;
  }
}

// ------------- transpose-convert: out[z][n][k] = bf16(in[z][k][n]) -------------
__global__ __launch_bounds__(256) void tcvt(const float* __restrict__ in,
                                            u16* __restrict__ out, int K, int N,
                                            long s_in, long s_out) {
  __shared__ float t[32][33];
  const int z = blockIdx.z;
  in += (long)z * s_in;
  out += (long)z * s_out;
  const int n0 = blockIdx.x * 32, k0 = blockIdx.y * 32;
  const int tx = threadIdx.x & 31, ty = threadIdx.x >> 5;
#pragma unroll
  for (int i = 0; i < 32; i += 8) t[ty + i][tx] = in[(long)(k0 + ty + i) * N + n0 + tx];
  __syncthreads();
#pragma unroll
  for (int i = 0; i < 32; i += 8)
    out[(long)(n0 + ty + i) * K + k0 + tx] = f2bf(t[tx][ty + i]);
}

// ------------- concat biases ----
__global__ __launch_bounds__(256) void biascat(const float* __restrict__ bq,
                                               const float* __restrict__ bk,
                                               const float* __restrict__ bv,
                                               float* __restrict__ o) {
  int i = blockIdx.x * 256 + threadIdx.x;  // grid 48
  float v = (i < 4096) ? bq[i] : ((i < 8192) ? bk[i - 4096] : bv[i - 8192]);
  o[i] = v;
}

// ------------- denominator reduce: drow[z][row] = sum_p dpart[z][p][row] ----
__global__ __launch_bounds__(256) void dred(const float* __restrict__ dpart,
                                            float* __restrict__ drow) {
  int t = blockIdx.x * 256 + threadIdx.x;  // grid 32 -> 8192 threads
  int z = t >> 11, row = t & 2047;
  float s = 0.f;
#pragma unroll
  for (int p = 0; p < 32; ++p) s += dpart[((long)z * 32 + p) * 2048 + row];
  drow[t] = s;
}

// ---------------- tiled MFMA GEMM, B^T only, 128x128, LDS double-buffered ----
// C[z] = A[z] @ B[z]^T * scale (+ bias[z*sBias + n]) (+= C if ACC)
// OUT_MODE: 0 = f32, 1 = bf16,
//           3 = QKV fused: z<2 bf16 normal, z==2 bf16 transposed-per-batch,
//           4 = scores: bf16 exp(acc*scale), per-row partials -> drow (as dpart)
//           5 = PV: bf16 (acc * 1/drow[row])
// K-loop: stage(t+1 -> buf^1) issued BEFORE compute(t); __syncthreads at the
// end of the iteration drains vmcnt(0) — the stage latency overlaps this
// tile's ds_read+MFMA instead of being exposed (T3-minimum 2-phase).
__device__ __forceinline__ int lds_slot(int row, int ks) {
  return row * 4 + (ks ^ ((row >> 1) & 3));
}

template <int OUT_MODE, int HAS_BIAS, int ACC>
__global__ __launch_bounds__(256, 4) void gemm_bt(
    const u16* __restrict__ A, const u16* __restrict__ Bm, void* __restrict__ Cp,
    const float* __restrict__ bias, float* __restrict__ drow,
    int K, int lda, int ldb, int ldc,
    long sA, long sB, long sC, long sBias, float scale) {
  __shared__ u16 Al[2][BM * BK];
  __shared__ u16 Bl[2][BN * BK];
  int bx, by, z;
  swz_decomp(bx, by, z);
  A += (long)z * sA;
  Bm += (long)z * sB;
  const long coff = (long)z * sC;
  const int bm = by * BM, bn = bx * BN;
  const int tid = threadIdx.x;
  const int lane = tid & 63;
  const int w = tid >> 6;
  const int wr = w >> 1, wc = w & 1;
  f32x4 acc[4][4] = {};

  // per-lane staging geometry (constant across K-steps)
  auto stage = [&](u16* Ad, u16* Bd, int k0) {
#pragma unroll
    for (int it = 0; it < 2; ++it) {
      const int sbase = w * 128 + it * 64;
      const int slot = sbase + lane;
      const int row = slot >> 2;
      const int j = (slot & 3) ^ ((row >> 1) & 3);  // inverse swizzle on global src
      gload_lds16(A + (long)(bm + row) * lda + (k0 + j * 8), Ad + sbase * 8);
      gload_lds16(Bm + (long)(bn + row) * ldb + (k0 + j * 8), Bd + sbase * 8);
    }
  };

  stage(Al[0], Bl[0], 0);
  __syncthreads();  // drains vmcnt(0): tile 0 landed
  int cur = 0;
  for (int k0 = 0; k0 < K; k0 += BK) {
    const int nxt = cur ^ 1;
    if (k0 + BK < K) stage(Al[nxt], Bl[nxt], k0 + BK);  // prefetch next tile
    const int ks = lane >> 4;
    s16x8 a[4], b[4];
#pragma unroll
    for (int i = 0; i < 4; i++) {
      int row = wr * 64 + i * 16 + (lane & 15);
      a[i] = *(const s16x8a*)&Al[cur][lds_slot(row, ks) * 8];
    }
#pragma unroll
    for (int j = 0; j < 4; j++) {
      int row = wc * 64 + j * 16 + (lane & 15);
      b[j] = *(const s16x8a*)&Bl[cur][lds_slot(row, ks) * 8];
    }
#pragma unroll
    for (int i = 0; i < 4; i++)
#pragma unroll
      for (int j = 0; j < 4; j++)
        acc[i][j] = __builtin_amdgcn_mfma_f32_16x16x32_bf16(a[i], b[j], acc[i][j], 0, 0, 0);
    __syncthreads();  // drains vmcnt(0): next tile landed; buf[cur] reads done
    cur = nxt;
  }

  // epilogue: C/D layout col = lane&15, row = (lane>>4)*4 + reg
  if (OUT_MODE == 4) {
    // scores: write bf16 exp(acc*scale); per-row partial sums -> dpart (no atomics)
#pragma unroll
    for (int i = 0; i < 4; i++) {
      int mbase = bm + wr * 64 + i * 16 + ((lane >> 4) << 2);
#pragma unroll
      for (int r = 0; r < 4; r++) {
        const int mm = mbase + r;
        float rowsum = 0.f;
#pragma unroll
        for (int j = 0; j < 4; j++) {
          int n = bn + wc * 64 + j * 16 + (lane & 15);
          float e = __expf(acc[i][j][r] * scale);
          ((u16a*)Cp)[coff + (long)mm * ldc + n] = f2bf(e);
          rowsum += e;
        }
        rowsum += __shfl_xor(rowsum, 1, 64);
        rowsum += __shfl_xor(rowsum, 2, 64);
        rowsum += __shfl_xor(rowsum, 4, 64);
        rowsum += __shfl_xor(rowsum, 8, 64);
        if ((lane & 15) == 0)
          drow[((long)z * 32 + (bx * 2 + wc)) * S_ + mm] = rowsum;
      }
    }
    return;
  }
  if (OUT_MODE == 5) {
    // PV: divide by the row denominator
#pragma unroll
    for (int i = 0; i < 4; i++) {
      int mbase = bm + wr * 64 + i * 16 + ((lane >> 4) << 2);
      float inv[4];
#pragma unroll
      for (int r = 0; r < 4; r++) inv[r] = 1.0f / drow[(long)z * S_ + mbase + r];
#pragma unroll
      for (int j = 0; j < 4; j++) {
        int n = bn + wc * 64 + j * 16 + (lane & 15);
#pragma unroll
        for (int r = 0; r < 4; r++) {
          ((u16a*)Cp)[coff + (long)(mbase + r) * ldc + n] = f2bf(acc[i][j][r] * inv[r]);
        }
      }
    }
    return;
  }
  const bool tpose = (OUT_MODE == 3 && z == 2);
#pragma unroll
  for (int i = 0; i < 4; i++) {
    int mbase = bm + wr * 64 + i * 16 + ((lane >> 4) << 2);
#pragma unroll
    for (int j = 0; j < 4; j++) {
      int n = bn + wc * 64 + j * 16 + (lane & 15);
      float bv = 0.f;
      if (HAS_BIAS) bv = bias[z * sBias + n];
      if (tpose) {
        ushort4 o;
        o.x = f2bf(acc[i][j][0] * scale + bv);
        o.y = f2bf(acc[i][j][1] * scale + bv);
        o.z = f2bf(acc[i][j][2] * scale + bv);
        o.w = f2bf(acc[i][j][3] * scale + bv);
        long idx = coff + (long)(mbase >> 11) * ((long)D_ * S_) + (long)n * S_ + (mbase & 2047);
        *(ushort4a*)&((u16a*)Cp)[idx] = o;
      } else {
#pragma unroll
        for (int r = 0; r < 4; r++) {
          float v = acc[i][j][r] * scale + bv;
          long idx = coff + (long)(mbase + r) * ldc + n;
          if (OUT_MODE == 1 || OUT_MODE == 3) {
            ((u16a*)Cp)[idx] = f2bf(v);
          } else {
            float* Cf = (float*)Cp;
            Cf[idx] = ACC ? (Cf[idx] + v) : v;
          }
        }
      }
    }
  }
}

// ---------------- LayerNorm over 1024 ----------------
__global__ __launch_bounds__(256) void ln_kernel(
    const float* __restrict__ X, const float* __restrict__ R,
    const float* __restrict__ g, const float* __restrict__ be,
    float* __restrict__ Y, u16* __restrict__ Yb) {
  const long row = blockIdx.x;
  const int t = threadIdx.x, lane = t & 63, w = t >> 6;
  const long base = row * 1024 + t * 4;
  float4 a = *(const float4a*)(X + base);
  float4 b = *(const float4a*)(R + base);
  float v0 = a.x + b.x, v1 = a.y + b.y, v2 = a.z + b.z, v3 = a.w + b.w;
  float s = v0 + v1 + v2 + v3;
  float q = v0 * v0 + v1 * v1 + v2 * v2 + v3 * v3;
#pragma unroll
  for (int o = 32; o > 0; o >>= 1) { s += __shfl_xor(s, o, 64); q += __shfl_xor(q, o, 64); }
  __shared__ float rs[4], rq[4];
  if (lane == 0) { rs[w] = s; rq[w] = q; }
  __syncthreads();
  s = rs[0] + rs[1] + rs[2] + rs[3];
  q = rq[0] + rq[1] + rq[2] + rq[3];
  const float mu = s * (1.f / 1024.f);
  const float var = q * (1.f / 1024.f) - mu * mu;
  const float rstd = rsqrtf(var + 1e-5f);
  float4 gv = *(const float4a*)(g + t * 4);
  float4 bv = *(const float4a*)(be + t * 4);
  float o0 = (v0 - mu) * rstd * gv.x + bv.x;
  float o1 = (v1 - mu) * rstd * gv.y + bv.y;
  float o2 = (v2 - mu) * rstd * gv.z + bv.z;
  float o3 = (v3 - mu) * rstd * gv.w + bv.w;
  float4 o4; o4.x = o0; o4.y = o1; o4.z = o2; o4.w = o3;
  *(float4a*)(Y + base) = o4;
  if (Yb) {
    ushort4 ob; ob.x = f2bf(o0); ob.y = f2bf(o1); ob.z = f2bf(o2); ob.w = f2bf(o3);
    *(ushort4a*)(Yb + base) = ob;
  }
}

extern "C" void kernel_launch(void* const* d_in, const int* in_sizes, int n_in,
                              void* d_out, int out_size, void* d_ws, size_t ws_size,
                              hipStream_t stream) {
  const float* x   = (const float*)d_in[0];
  const float* Wq  = (const float*)d_in[1];
  const float* bq  = (const float*)d_in[2];
  const float* Wk  = (const float*)d_in[3];
  const float* bk  = (const float*)d_in[4];
  const float* Wv  = (const float*)d_in[5];
  const float* bv  = (const float*)d_in[6];
  const float* W1  = (const float*)d_in[7];
  const float* b1  = (const float*)d_in[8];
  const float* g1  = (const float*)d_in[9];
  const float* be1 = (const float*)d_in[10];
  const float* W2  = (const float*)d_in[11];
  const float* b2  = (const float*)d_in[12];
  const float* g2  = (const float*)d_in[13];
  const float* be2 = (const float*)d_in[14];
  float* out = (float*)d_out;

  // ---- workspace layouts.
  // base (fallback): peak 186,646,528 B. Cc path: peak 203,423,744 B.
  const size_t NEED_BASE = 186646528ULL;
  const size_t NEED_CC   = 203423744ULL;
  if (ws_size < NEED_BASE) return;
  const bool useCc = (ws_size >= NEED_CC);
  char* ws = (char*)d_ws;
  u16* xb  = (u16*)(ws + 0L);           // 16,777,216  [M][D]
  u16* Wqt = (u16*)(ws + 16777216L);    //  8,388,608  [H][D][D] (out,in)
  u16* Wkt = (u16*)(ws + 25165824L);    //  8,388,608
  u16* Wvt = (u16*)(ws + 33554432L);    //  8,388,608
  u16* W1t = (u16*)(ws + 41943040L);    //  8,388,608  [D][H*D]
  u16* W2t = (u16*)(ws + 50331648L);    //  2,097,152  [D][D]
  u16* Qh  = (u16*)(ws + 52428800L);    // 16,777,216  [M][D]
  u16* Kh  = (u16*)(ws + 69206016L);    // 16,777,216
  u16* Vt  = (u16*)(ws + 85983232L);    // 16,777,216  [B][D][S]
  u16* Sbh = (u16*)(ws + 102760448L);   // 33,554,432  [B][S][S] exp-scores
  u16* Cc   = (u16*)(ws + 136314880L);  // Cc path: 67,108,864 concat PV out
  u16* Ch   = (u16*)(ws + 136314880L);  // fallback: 16.8MB per-head PV out
  float* proj = useCc ? (float*)Sbh : (float*)(ws + 153092096L);
  float* y  = (float*)Qh;               // f32 33.5MB (Qh+Kh dead after head loop)
  u16*   yb = Vt;                       // bf16 (Vt dead)
  float* z2 = useCc ? (float*)Cc : proj;
  float* biasQKV = out;                 // d_out scratch: [0,12288) floats
  float* dsum  = out + 16384;           // [B][S] f32, reused per head
  float* dpart = out + 65536;           // [B][32][S] f32 partials, reused per head

  dim3 blk(256);
  {
    long n4 = (long)M_ * D_ / 4;
    hipLaunchKernelGGL(cvt_f32_bf16, dim3(4096), blk, 0, stream, x, xb, n4);
  }
  hipLaunchKernelGGL(tcvt, dim3(32, 32, H_), blk, 0, stream, Wq, Wqt, D_, D_,
                     (long)D_ * D_, (long)D_ * D_);
  hipLaunchKernelGGL(tcvt, dim3(32, 32, H_), blk, 0, stream, Wk, Wkt, D_, D_,
                     (long)D_ * D_, (long)D_ * D_);
  hipLaunchKernelGGL(tcvt, dim3(32, 32, H_), blk, 0, stream, Wv, Wvt, D_, D_,
                     (long)D_ * D_, (long)D_ * D_);
  hipLaunchKernelGGL(tcvt, dim3(32, 128, 1), blk, 0, stream, W1, W1t, H_ * D_, D_, 0L, 0L);
  hipLaunchKernelGGL(tcvt, dim3(32, 32, 1), blk, 0, stream, W2, W2t, D_, D_, 0L, 0L);
  hipLaunchKernelGGL(biascat, dim3(48), blk, 0, stream, bq, bk, bv, biasQKV);

  for (int h = 0; h < H_; ++h) {
    const long wo = (long)h * D_ * D_;
    // fused QKV: z=0 Q, z=1 K (normal), z=2 V (transposed)
    hipLaunchKernelGGL((gemm_bt<3, 1, 0>), dim3(8, 64, 3), blk, 0, stream,
                       xb, Wqt + wo, (void*)Qh, biasQKV + (long)h * D_, (float*)nullptr,
                       D_, D_, D_, D_,
                       0L, (long)H_ * D_ * D_, (long)M_ * D_, (long)H_ * D_, 1.0f);
    // scores: Sbh[b] = exp(Q K^T / 32), per-row partial sums -> dpart
    hipLaunchKernelGGL((gemm_bt<4, 0, 0>), dim3(16, 16, B_), blk, 0, stream,
                       Qh, Kh, (void*)Sbh, (const float*)nullptr, dpart,
                       D_, D_, D_, S_,
                       (long)S_ * D_, (long)S_ * D_, (long)S_ * S_, 0L, 0.03125f);
    // reduce partials -> dsum
    hipLaunchKernelGGL(dred, dim3(32), blk, 0, stream, dpart, dsum);
    // PV with row-normalize epilogue
    if (useCc) {
      hipLaunchKernelGGL((gemm_bt<5, 0, 0>), dim3(8, 16, B_), blk, 0, stream,
                         Sbh, Vt, (void*)(Cc + (long)h * D_), (const float*)nullptr, dsum,
                         S_, S_, S_, H_ * D_,
                         (long)S_ * S_, (long)D_ * S_, (long)S_ * H_ * D_, 0L, 1.0f);
    } else {
      hipLaunchKernelGGL((gemm_bt<5, 0, 0>), dim3(8, 16, B_), blk, 0, stream,
                         Sbh, Vt, (void*)Ch, (const float*)nullptr, dsum,
                         S_, S_, S_, D_,
                         (long)S_ * S_, (long)D_ * S_, (long)S_ * D_, 0L, 1.0f);
      if (h == 0) {
        hipLaunchKernelGGL((gemm_bt<0, 1, 0>), dim3(8, 64, 1), blk, 0, stream,
                           Ch, W1t + (long)h * D_, (void*)proj, b1, (float*)nullptr,
                           D_, D_, H_ * D_, D_, 0L, 0L, 0L, 0L, 1.0f);
      } else {
        hipLaunchKernelGGL((gemm_bt<0, 0, 1>), dim3(8, 64, 1), blk, 0, stream,
                           Ch, W1t + (long)h * D_, (void*)proj, (const float*)nullptr,
                           (float*)nullptr, D_, D_, H_ * D_, D_, 0L, 0L, 0L, 0L, 1.0f);
      }
    }
  }

  if (useCc) {
    // single W1: proj = Cc @ W1t^T + b1, K = 4096
    hipLaunchKernelGGL((gemm_bt<0, 1, 0>), dim3(8, 64, 1), blk, 0, stream,
                       Cc, W1t, (void*)proj, b1, (float*)nullptr,
                       H_ * D_, H_ * D_, H_ * D_, D_, 0L, 0L, 0L, 0L, 1.0f);
  }

  // ---- LN1: y = LN(x + proj); also bf16 copy yb
  hipLaunchKernelGGL(ln_kernel, dim3(M_), blk, 0, stream, x, proj, g1, be1, y, yb);

  // ---- W2: z2 = yb @ W2t^T + b2 (f32)
  hipLaunchKernelGGL((gemm_bt<0, 1, 0>), dim3(8, 64, 1), blk, 0, stream,
                     yb, W2t, (void*)z2, b2, (float*)nullptr,
                     D_, D_, D_, D_, 0L, 0L, 0L, 0L, 1.0f);

  // ---- LN2: out = LN(y + z2)
  hipLaunchKernelGGL(ln_kernel, dim3(M_), blk, 0, stream, y, z2, g2, be2, out, (u16*)nullptr);
}

// Round 10
// 821.132 us; speedup vs baseline: 1.0459x; 1.0459x over previous
//
#include <hip/hip_runtime.h>

using u16 = unsigned short;
using u32 = unsigned int;
typedef __attribute__((ext_vector_type(8))) short s16x8;
typedef __attribute__((ext_vector_type(4))) float f32x4;

typedef uint4   __attribute__((may_alias)) uint4a;
typedef ushort4 __attribute__((may_alias)) ushort4a;
typedef float4  __attribute__((may_alias)) float4a;
typedef u16     __attribute__((may_alias)) u16a;
typedef s16x8   __attribute__((may_alias)) s16x8a;

#define D_ 1024
#define H_ 4
#define B_ 4
#define S_ 2048
#define M_ 8192  /* B_*S_ */

#define BM 128
#define BN 128
#define BK 32

__device__ __forceinline__ float bf2f(u16 u) { return __uint_as_float(((u32)u) << 16); }
__device__ __forceinline__ u16 f2bf(float f) {
  u32 b = __float_as_uint(f);
  return (u16)((b + 0x7fffu + ((b >> 16) & 1u)) >> 16);
}

__device__ __forceinline__ void gload_lds16(const u16* g, u16* l) {
  __builtin_amdgcn_global_load_lds(
      (const __attribute__((address_space(1))) void*)g,
      (__attribute__((address_space(3))) void*)l, 16, 0, 0);
}

#define FENCE asm volatile("" ::: "memory")
#define BAR do { FENCE; __builtin_amdgcn_s_barrier(); FENCE; } while (0)
#define VMC4 asm volatile("s_waitcnt vmcnt(4)" ::: "memory")

// XCD-bijective swizzle + 4x4 quad decomposition, z folded into x-axis.
// Requires nwg%16==0, (gx*gz)%4==0, gy%4==0 (all our grids satisfy).
__device__ __forceinline__ void swz_decomp(int& x, int& y, int& z) {
  const int gx = gridDim.x, gy = gridDim.y;
  const int nwg = gx * gy * gridDim.z;
  const int flat = (blockIdx.z * gy + blockIdx.y) * gx + blockIdx.x;
  const int swz = (flat & 7) * (nwg >> 3) + (flat >> 3);
  const int t = swz >> 4, i = swz & 15;
  const int tiles_X = (gx * gridDim.z) >> 2;
  const int X = (t % tiles_X) * 4 + (i & 3);
  y = (t / tiles_X) * 4 + (i >> 2);
  z = X / gx;
  x = X % gx;
}

// ---------------- f32 -> bf16 convert ----------------
__global__ __launch_bounds__(256) void cvt_f32_bf16(const float* __restrict__ in,
                                                    u16* __restrict__ out, long n4) {
  long stride = (long)gridDim.x * blockDim.x;
  for (long i = (long)blockIdx.x * blockDim.x + threadIdx.x; i < n4; i += stride) {
    float4 v = ((const float4a*)in)[i];
    ushort4 o;
    o.x = f2bf(v.x); o.y = f2bf(v.y); o.z = f2bf(v.z); o.w = f2bf(v.w);
    ((ushort4a*)out)[i] = o;
  }
}

// ------------- transpose-convert: out[z][n][k] = bf16(in[z][k][n]) -------------
__global__ __launch_bounds__(256) void tcvt(const float* __restrict__ in,
                                            u16* __restrict__ out, int K, int N,
                                            long s_in, long s_out) {
  __shared__ float t[32][33];
  const int z = blockIdx.z;
  in += (long)z * s_in;
  out += (long)z * s_out;
  const int n0 = blockIdx.x * 32, k0 = blockIdx.y * 32;
  const int tx = threadIdx.x & 31, ty = threadIdx.x >> 5;
#pragma unroll
  for (int i = 0; i < 32; i += 8) t[ty + i][tx] = in[(long)(k0 + ty + i) * N + n0 + tx];
  __syncthreads();
#pragma unroll
  for (int i = 0; i < 32; i += 8)
    out[(long)(n0 + ty + i) * K + k0 + tx] = f2bf(t[tx][ty + i]);
}

// ------------- concat biases ----
__global__ __launch_bounds__(256) void biascat(const float* __restrict__ bq,
                                               const float* __restrict__ bk,
                                               const float* __restrict__ bv,
                                               float* __restrict__ o) {
  int i = blockIdx.x * 256 + threadIdx.x;  // grid 48
  float v = (i < 4096) ? bq[i] : ((i < 8192) ? bk[i - 4096] : bv[i - 8192]);
  o[i] = v;
}

// ------------- denominator reduce: drow[z][row] = sum_p dpart[z][p][row] ----
__global__ __launch_bounds__(256) void dred(const float* __restrict__ dpart,
                                            float* __restrict__ drow) {
  int t = blockIdx.x * 256 + threadIdx.x;  // grid 32 -> 8192 threads
  int z = t >> 11, row = t & 2047;
  float s = 0.f;
#pragma unroll
  for (int p = 0; p < 32; ++p) s += dpart[((long)z * 32 + p) * 2048 + row];
  drow[t] = s;
}

// ============ 256x256 8-phase MFMA GEMM for SCORES only ============
// Sbh[z] = exp((Q[z] @ K[z]^T) / 32) bf16; per-row partial sums -> dpart.
// M=N=2048, K=1024 (nt2=8), lda=ldb=1024, ldc=2048. 512 threads, 8 waves.
// LDS per buffer: 256 rows x 8 chunks of 16B; chunk j of row r at slot
// r*8 + (j ^ (r&7)); staged linearly via global_load_lds with the inverse
// swizzle on the per-lane global source (r5-verified).
__device__ __forceinline__ s16x8 lds_frag(const u16* buf, int r, int jc) {
  return *(const s16x8a*)&buf[(((r << 3) + (jc ^ (r & 7)))) << 3];
}
__device__ __forceinline__ void readB(const u16* Bbuf, int wc, int lane, s16x8 (&bfr)[4][2]) {
#pragma unroll
  for (int j = 0; j < 4; ++j)
#pragma unroll
    for (int s = 0; s < 2; ++s)
      bfr[j][s] = lds_frag(Bbuf, wc * 64 + j * 16 + (lane & 15), 4 * s + (lane >> 4));
}
__device__ __forceinline__ void readA(const u16* Abuf, int q, int wr, int lane, s16x8 (&afr)[2][2]) {
#pragma unroll
  for (int il = 0; il < 2; ++il)
#pragma unroll
    for (int s = 0; s < 2; ++s)
      afr[il][s] = lds_frag(Abuf, wr * 128 + (q * 2 + il) * 16 + (lane & 15), 4 * s + (lane >> 4));
}
__device__ __forceinline__ void mfma_quad(const s16x8 (&afr)[2][2], const s16x8 (&bfr)[4][2],
                                          f32x4 (&acc)[8][4], int q) {
  __builtin_amdgcn_s_setprio(1);
#pragma unroll
  for (int s = 0; s < 2; ++s)
#pragma unroll
    for (int il = 0; il < 2; ++il)
#pragma unroll
      for (int j = 0; j < 4; ++j)
        acc[q * 2 + il][j] =
            __builtin_amdgcn_mfma_f32_16x16x32_bf16(afr[il][s], bfr[j][s], acc[q * 2 + il][j], 0, 0, 0);
  __builtin_amdgcn_s_setprio(0);
}

__global__ __launch_bounds__(512, 2) void gemm256x(
    const u16* __restrict__ A, const u16* __restrict__ Bm, u16* __restrict__ Cp,
    float* __restrict__ dpart) {
  __shared__ u16 Al[2][16384];
  __shared__ u16 Bl[2][16384];
  // bijective XCD-chunk swizzle over nwg=256 (8x8x4 grid)
  const int flat = (blockIdx.z * 8 + blockIdx.y) * 8 + blockIdx.x;
  const int swz = (flat & 7) * 32 + (flat >> 3);
  const int bx = swz & 7, by = (swz >> 3) & 7, z = swz >> 6;
  A += (long)z * ((long)S_ * D_);
  Bm += (long)z * ((long)S_ * D_);
  const long coff = (long)z * S_ * S_;
  const int bm = by * 256, bn = bx * 256;
  const int tid = threadIdx.x;
  const int lane = tid & 63;
  const int w = tid >> 6;            // 0..7
  const int wr = w >> 2, wc = w & 3; // 2 x 4 wave grid; per-wave 128x64 output
  f32x4 acc[8][4] = {};
  const int nt2 = D_ >> 7;  // 8 iterations; 2 K-tiles (of 64) each

  auto stage = [&](const u16* src, int b0, u16* lbuf, int h, int kt) {
    const int k0 = kt << 6;
#pragma unroll
    for (int it = 0; it < 2; ++it) {
      int c = w * 128 + it * 64 + lane;
      int row = h * 128 + (c >> 3);
      int j = (c & 7) ^ (row & 7);  // inverse swizzle on global source
      gload_lds16(src + (long)(b0 + row) * D_ + (k0 + j * 8),
                  lbuf + ((h * 1024 + w * 128 + it * 64) << 3));
    }
  };

  // prologue: A0<-t0, B0<-t0, B1<-t1
  stage(A, bm, Al[0], 0, 0);
  stage(A, bm, Al[0], 1, 0);
  stage(Bm, bn, Bl[0], 0, 0);
  stage(Bm, bn, Bl[0], 1, 0);
  stage(Bm, bn, Bl[1], 0, 1);
  stage(Bm, bn, Bl[1], 1, 1);
  VMC4;
  BAR;

  s16x8 bfr[4][2];
  for (int i2 = 0; i2 < nt2; ++i2) {
    const int t = i2 * 2;
    s16x8 afr[2][2];
    readB(Bl[0], wc, lane, bfr);
    readA(Al[0], 0, wr, lane, afr);
    stage(A, bm, Al[1], 0, t + 1);
    BAR;
    mfma_quad(afr, bfr, acc, 0);
    BAR;
    readA(Al[0], 1, wr, lane, afr);
    stage(A, bm, Al[1], 1, t + 1);
    BAR;
    mfma_quad(afr, bfr, acc, 1);
    BAR;
    readA(Al[0], 2, wr, lane, afr);
    stage(Bm, bn, Bl[0], 0, t + 2);
    BAR;
    mfma_quad(afr, bfr, acc, 2);
    BAR;
    readA(Al[0], 3, wr, lane, afr);
    stage(Bm, bn, Bl[0], 1, t + 2);
    BAR;
    mfma_quad(afr, bfr, acc, 3);
    VMC4;
    BAR;
    readB(Bl[1], wc, lane, bfr);
    readA(Al[1], 0, wr, lane, afr);
    stage(A, bm, Al[0], 0, t + 2);
    BAR;
    mfma_quad(afr, bfr, acc, 0);
    BAR;
    readA(Al[1], 1, wr, lane, afr);
    stage(A, bm, Al[0], 1, t + 2);
    BAR;
    mfma_quad(afr, bfr, acc, 1);
    BAR;
    readA(Al[1], 2, wr, lane, afr);
    stage(Bm, bn, Bl[1], 0, t + 3);
    BAR;
    mfma_quad(afr, bfr, acc, 2);
    BAR;
    readA(Al[1], 3, wr, lane, afr);
    stage(Bm, bn, Bl[1], 1, t + 3);
    BAR;
    mfma_quad(afr, bfr, acc, 3);
    VMC4;
    BAR;
  }

  // epilogue: exp(acc/32) -> bf16 store; per-row partials -> dpart[z][bx*4+wc]
#pragma unroll
  for (int i = 0; i < 8; i++) {
    int mbase = bm + wr * 128 + i * 16 + ((lane >> 4) << 2);
#pragma unroll
    for (int r = 0; r < 4; r++) {
      const int mm = mbase + r;
      float rowsum = 0.f;
#pragma unroll
      for (int j = 0; j < 4; j++) {
        int n = bn + wc * 64 + j * 16 + (lane & 15);
        float e = __expf(acc[i][j][r] * 0.03125f);
        ((u16a*)Cp)[coff + (long)mm * S_ + n] = f2bf(e);
        rowsum += e;
      }
      rowsum += __shfl_xor(rowsum, 1, 64);
      rowsum += __shfl_xor(rowsum, 2, 64);
      rowsum += __shfl_xor(rowsum, 4, 64);
      rowsum += __shfl_xor(rowsum, 8, 64);
      if ((lane & 15) == 0)
        dpart[((long)z * 32 + (bx * 4 + wc)) * S_ + mm] = rowsum;
    }
  }
}

// ---------------- tiled MFMA GEMM, B^T only, 128x128, LDS double-buffered ----
// OUT_MODE: 0 = f32, 1 = bf16,
//           3 = QKV fused: z<2 bf16 normal, z==2 bf16 transposed-per-batch,
//           5 = PV: bf16 (acc * 1/drow[row])
__device__ __forceinline__ int lds_slot(int row, int ks) {
  return row * 4 + (ks ^ ((row >> 1) & 3));
}

template <int OUT_MODE, int HAS_BIAS, int ACC>
__global__ __launch_bounds__(256, 4) void gemm_bt(
    const u16* __restrict__ A, const u16* __restrict__ Bm, void* __restrict__ Cp,
    const float* __restrict__ bias, float* __restrict__ drow,
    int K, int lda, int ldb, int ldc,
    long sA, long sB, long sC, long sBias, float scale) {
  __shared__ u16 Al[2][BM * BK];
  __shared__ u16 Bl[2][BN * BK];
  int bx, by, z;
  swz_decomp(bx, by, z);
  A += (long)z * sA;
  Bm += (long)z * sB;
  const long coff = (long)z * sC;
  const int bm = by * BM, bn = bx * BN;
  const int tid = threadIdx.x;
  const int lane = tid & 63;
  const int w = tid >> 6;
  const int wr = w >> 1, wc = w & 1;
  f32x4 acc[4][4] = {};

  auto stage = [&](u16* Ad, u16* Bd, int k0) {
#pragma unroll
    for (int it = 0; it < 2; ++it) {
      const int sbase = w * 128 + it * 64;
      const int slot = sbase + lane;
      const int row = slot >> 2;
      const int j = (slot & 3) ^ ((row >> 1) & 3);
      gload_lds16(A + (long)(bm + row) * lda + (k0 + j * 8), Ad + sbase * 8);
      gload_lds16(Bm + (long)(bn + row) * ldb + (k0 + j * 8), Bd + sbase * 8);
    }
  };

  stage(Al[0], Bl[0], 0);
  __syncthreads();
  int cur = 0;
  for (int k0 = 0; k0 < K; k0 += BK) {
    const int nxt = cur ^ 1;
    if (k0 + BK < K) stage(Al[nxt], Bl[nxt], k0 + BK);
    const int ks = lane >> 4;
    s16x8 a[4], b[4];
#pragma unroll
    for (int i = 0; i < 4; i++) {
      int row = wr * 64 + i * 16 + (lane & 15);
      a[i] = *(const s16x8a*)&Al[cur][lds_slot(row, ks) * 8];
    }
#pragma unroll
    for (int j = 0; j < 4; j++) {
      int row = wc * 64 + j * 16 + (lane & 15);
      b[j] = *(const s16x8a*)&Bl[cur][lds_slot(row, ks) * 8];
    }
#pragma unroll
    for (int i = 0; i < 4; i++)
#pragma unroll
      for (int j = 0; j < 4; j++)
        acc[i][j] = __builtin_amdgcn_mfma_f32_16x16x32_bf16(a[i], b[j], acc[i][j], 0, 0, 0);
    __syncthreads();
    cur = nxt;
  }

  if (OUT_MODE == 5) {
#pragma unroll
    for (int i = 0; i < 4; i++) {
      int mbase = bm + wr * 64 + i * 16 + ((lane >> 4) << 2);
      float inv[4];
#pragma unroll
      for (int r = 0; r < 4; r++) inv[r] = 1.0f / drow[(long)z * S_ + mbase + r];
#pragma unroll
      for (int j = 0; j < 4; j++) {
        int n = bn + wc * 64 + j * 16 + (lane & 15);
#pragma unroll
        for (int r = 0; r < 4; r++) {
          ((u16a*)Cp)[coff + (long)(mbase + r) * ldc + n] = f2bf(acc[i][j][r] * inv[r]);
        }
      }
    }
    return;
  }
  const bool tpose = (OUT_MODE == 3 && z == 2);
#pragma unroll
  for (int i = 0; i < 4; i++) {
    int mbase = bm + wr * 64 + i * 16 + ((lane >> 4) << 2);
#pragma unroll
    for (int j = 0; j < 4; j++) {
      int n = bn + wc * 64 + j * 16 + (lane & 15);
      float bv = 0.f;
      if (HAS_BIAS) bv = bias[z * sBias + n];
      if (tpose) {
        ushort4 o;
        o.x = f2bf(acc[i][j][0] * scale + bv);
        o.y = f2bf(acc[i][j][1] * scale + bv);
        o.z = f2bf(acc[i][j][2] * scale + bv);
        o.w = f2bf(acc[i][j][3] * scale + bv);
        long idx = coff + (long)(mbase >> 11) * ((long)D_ * S_) + (long)n * S_ + (mbase & 2047);
        *(ushort4a*)&((u16a*)Cp)[idx] = o;
      } else {
#pragma unroll
        for (int r = 0; r < 4; r++) {
          float v = acc[i][j][r] * scale + bv;
          long idx = coff + (long)(mbase + r) * ldc + n;
          if (OUT_MODE == 1 || OUT_MODE == 3) {
            ((u16a*)Cp)[idx] = f2bf(v);
          } else {
            float* Cf = (float*)Cp;
            Cf[idx] = ACC ? (Cf[idx] + v) : v;
          }
        }
      }
    }
  }
}

// ---------------- LayerNorm over 1024 ----------------
__global__ __launch_bounds__(256) void ln_kernel(
    const float* __restrict__ X, const float* __restrict__ R,
    const float* __restrict__ g, const float* __restrict__ be,
    float* __restrict__ Y, u16* __restrict__ Yb) {
  const long row = blockIdx.x;
  const int t = threadIdx.x, lane = t & 63, w = t >> 6;
  const long base = row * 1024 + t * 4;
  float4 a = *(const float4a*)(X + base);
  float4 b = *(const float4a*)(R + base);
  float v0 = a.x + b.x, v1 = a.y + b.y, v2 = a.z + b.z, v3 = a.w + b.w;
  float s = v0 + v1 + v2 + v3;
  float q = v0 * v0 + v1 * v1 + v2 * v2 + v3 * v3;
#pragma unroll
  for (int o = 32; o > 0; o >>= 1) { s += __shfl_xor(s, o, 64); q += __shfl_xor(q, o, 64); }
  __shared__ float rs[4], rq[4];
  if (lane == 0) { rs[w] = s; rq[w] = q; }
  __syncthreads();
  s = rs[0] + rs[1] + rs[2] + rs[3];
  q = rq[0] + rq[1] + rq[2] + rq[3];
  const float mu = s * (1.f / 1024.f);
  const float var = q * (1.f / 1024.f) - mu * mu;
  const float rstd = rsqrtf(var + 1e-5f);
  float4 gv = *(const float4a*)(g + t * 4);
  float4 bv = *(const float4a*)(be + t * 4);
  float o0 = (v0 - mu) * rstd * gv.x + bv.x;
  float o1 = (v1 - mu) * rstd * gv.y + bv.y;
  float o2 = (v2 - mu) * rstd * gv.z + bv.z;
  float o3 = (v3 - mu) * rstd * gv.w + bv.w;
  float4 o4; o4.x = o0; o4.y = o1; o4.z = o2; o4.w = o3;
  *(float4a*)(Y + base) = o4;
  if (Yb) {
    ushort4 ob; ob.x = f2bf(o0); ob.y = f2bf(o1); ob.z = f2bf(o2); ob.w = f2bf(o3);
    *(ushort4a*)(Yb + base) = ob;
  }
}

extern "C" void kernel_launch(void* const* d_in, const int* in_sizes, int n_in,
                              void* d_out, int out_size, void* d_ws, size_t ws_size,
                              hipStream_t stream) {
  const float* x   = (const float*)d_in[0];
  const float* Wq  = (const float*)d_in[1];
  const float* bq  = (const float*)d_in[2];
  const float* Wk  = (const float*)d_in[3];
  const float* bk  = (const float*)d_in[4];
  const float* Wv  = (const float*)d_in[5];
  const float* bv  = (const float*)d_in[6];
  const float* W1  = (const float*)d_in[7];
  const float* b1  = (const float*)d_in[8];
  const float* g1  = (const float*)d_in[9];
  const float* be1 = (const float*)d_in[10];
  const float* W2  = (const float*)d_in[11];
  const float* b2  = (const float*)d_in[12];
  const float* g2  = (const float*)d_in[13];
  const float* be2 = (const float*)d_in[14];
  float* out = (float*)d_out;

  const size_t NEED_BASE = 186646528ULL;
  const size_t NEED_CC   = 203423744ULL;
  if (ws_size < NEED_BASE) return;
  const bool useCc = (ws_size >= NEED_CC);
  char* ws = (char*)d_ws;
  u16* xb  = (u16*)(ws + 0L);           // 16,777,216  [M][D]
  u16* Wqt = (u16*)(ws + 16777216L);    //  8,388,608  [H][D][D] (out,in)
  u16* Wkt = (u16*)(ws + 25165824L);    //  8,388,608
  u16* Wvt = (u16*)(ws + 33554432L);    //  8,388,608
  u16* W1t = (u16*)(ws + 41943040L);    //  8,388,608  [D][H*D]
  u16* W2t = (u16*)(ws + 50331648L);    //  2,097,152  [D][D]
  u16* Qh  = (u16*)(ws + 52428800L);    // 16,777,216  [M][D]
  u16* Kh  = (u16*)(ws + 69206016L);    // 16,777,216
  u16* Vt  = (u16*)(ws + 85983232L);    // 16,777,216  [B][D][S]
  u16* Sbh = (u16*)(ws + 102760448L);   // 33,554,432  [B][S][S] exp-scores
  u16* Cc   = (u16*)(ws + 136314880L);  // Cc path: 67,108,864 concat PV out
  u16* Ch   = (u16*)(ws + 136314880L);  // fallback: 16.8MB per-head PV out
  float* proj = useCc ? (float*)Sbh : (float*)(ws + 153092096L);
  float* y  = (float*)Qh;               // f32 33.5MB (Qh+Kh dead after head loop)
  u16*   yb = Vt;                       // bf16 (Vt dead)
  float* z2 = useCc ? (float*)Cc : proj;
  float* biasQKV = out;                 // d_out scratch: [0,12288) floats
  float* dsum  = out + 16384;           // [B][S] f32, reused per head
  float* dpart = out + 65536;           // [B][32][S] f32 partials, reused per head

  dim3 blk(256);
  {
    long n4 = (long)M_ * D_ / 4;
    hipLaunchKernelGGL(cvt_f32_bf16, dim3(4096), blk, 0, stream, x, xb, n4);
  }
  hipLaunchKernelGGL(tcvt, dim3(32, 32, H_), blk, 0, stream, Wq, Wqt, D_, D_,
                     (long)D_ * D_, (long)D_ * D_);
  hipLaunchKernelGGL(tcvt, dim3(32, 32, H_), blk, 0, stream, Wk, Wkt, D_, D_,
                     (long)D_ * D_, (long)D_ * D_);
  hipLaunchKernelGGL(tcvt, dim3(32, 32, H_), blk, 0, stream, Wv, Wvt, D_, D_,
                     (long)D_ * D_, (long)D_ * D_);
  hipLaunchKernelGGL(tcvt, dim3(32, 128, 1), blk, 0, stream, W1, W1t, H_ * D_, D_, 0L, 0L);
  hipLaunchKernelGGL(tcvt, dim3(32, 32, 1), blk, 0, stream, W2, W2t, D_, D_, 0L, 0L);
  hipLaunchKernelGGL(biascat, dim3(48), blk, 0, stream, bq, bk, bv, biasQKV);

  for (int h = 0; h < H_; ++h) {
    const long wo = (long)h * D_ * D_;
    // fused QKV: z=0 Q, z=1 K (normal), z=2 V (transposed)
    hipLaunchKernelGGL((gemm_bt<3, 1, 0>), dim3(8, 64, 3), blk, 0, stream,
                       xb, Wqt + wo, (void*)Qh, biasQKV + (long)h * D_, (float*)nullptr,
                       D_, D_, D_, D_,
                       0L, (long)H_ * D_ * D_, (long)M_ * D_, (long)H_ * D_, 1.0f);
    // scores: 8-phase 256^2 kernel; Sbh = exp(QK^T/32), partials -> dpart
    hipLaunchKernelGGL(gemm256x, dim3(8, 8, B_), dim3(512), 0, stream,
                       Qh, Kh, Sbh, dpart);
    // reduce partials -> dsum
    hipLaunchKernelGGL(dred, dim3(32), blk, 0, stream, dpart, dsum);
    // PV with row-normalize epilogue
    if (useCc) {
      hipLaunchKernelGGL((gemm_bt<5, 0, 0>), dim3(8, 16, B_), blk, 0, stream,
                         Sbh, Vt, (void*)(Cc + (long)h * D_), (const float*)nullptr, dsum,
                         S_, S_, S_, H_ * D_,
                         (long)S_ * S_, (long)D_ * S_, (long)S_ * H_ * D_, 0L, 1.0f);
    } else {
      hipLaunchKernelGGL((gemm_bt<5, 0, 0>), dim3(8, 16, B_), blk, 0, stream,
                         Sbh, Vt, (void*)Ch, (const float*)nullptr, dsum,
                         S_, S_, S_, D_,
                         (long)S_ * S_, (long)D_ * S_, (long)S_ * D_, 0L, 1.0f);
      if (h == 0) {
        hipLaunchKernelGGL((gemm_bt<0, 1, 0>), dim3(8, 64, 1), blk, 0, stream,
                           Ch, W1t + (long)h * D_, (void*)proj, b1, (float*)nullptr,
                           D_, D_, H_ * D_, D_, 0L, 0L, 0L, 0L, 1.0f);
      } else {
        hipLaunchKernelGGL((gemm_bt<0, 0, 1>), dim3(8, 64, 1), blk, 0, stream,
                           Ch, W1t + (long)h * D_, (void*)proj, (const float*)nullptr,
                           (float*)nullptr, D_, D_, H_ * D_, D_, 0L, 0L, 0L, 0L, 1.0f);
      }
    }
  }

  if (useCc) {
    // single W1: proj = Cc @ W1t^T + b1, K = 4096
    hipLaunchKernelGGL((gemm_bt<0, 1, 0>), dim3(8, 64, 1), blk, 0, stream,
                       Cc, W1t, (void*)proj, b1, (float*)nullptr,
                       H_ * D_, H_ * D_, H_ * D_, D_, 0L, 0L, 0L, 0L, 1.0f);
  }

  // ---- LN1: y = LN(x + proj); also bf16 copy yb
  hipLaunchKernelGGL(ln_kernel, dim3(M_), blk, 0, stream, x, proj, g1, be1, y, yb);

  // ---- W2: z2 = yb @ W2t^T + b2 (f32)
  hipLaunchKernelGGL((gemm_bt<0, 1, 0>), dim3(8, 64, 1), blk, 0, stream,
                     yb, W2t, (void*)z2, b2, (float*)nullptr,
                     D_, D_, D_, D_, 0L, 0L, 0L, 0L, 1.0f);

  // ---- LN2: out = LN(y + z2)
  hipLaunchKernelGGL(ln_kernel, dim3(M_), blk, 0, stream, y, z2, g2, be2, out, (u16*)nullptr);
}